// Round 6
// baseline (329.655 us; speedup 1.0000x reference)
//
#include <hip/hip_runtime.h>

// PatchAttacker: B=32 images 512x512x3, N=6 boxes, patch 512x512x3.
// Final pixel = bilinear(patch) of the LAST valid covering patch box, else image.
// v6: software-pipelined streaming. Diagnosis: v1-v5 all land at 62-65us with
//     minimal traffic (153MB, floor 24us) and all pipes <52% -> exposed memory
//     latency; per-wave phases serialize so in-flight bytes/CU << the ~12KB
//     Little's-law requirement. Fix: 4 iterations x 2px per thread, fully
//     unrolled 2-deep pipeline (issue(i+1) before consume(i)) so each wave has
//     ~10 VMEM ops in flight continuously. No LDS, no barrier: normal
//     (allocating) 24B-stride stores merge in L2 with no write amplification
//     (v1 counter evidence; only NT no-allocate stores amplified in v2).
//     Bit-exact formulas and predication carried over from v5 (absmax 0.0).

#define Bn 32
#define Nn 6
#define Hh 512
#define Ww 512
#define Pp 512

typedef float f32x4 __attribute__((ext_vector_type(4)));
typedef float f32x4u __attribute__((ext_vector_type(4), aligned(4)));
typedef float f32x2u __attribute__((ext_vector_type(2), aligned(4)));

struct BoxP {
    int   y0b, x0b, hI, wI;
    float syscale, winv;
    int   valid, pad;
};

__global__ __launch_bounds__(192) void box_setup_kernel(
    const float* __restrict__ boxes,   // [B,N,4]
    BoxP* __restrict__ bp)             // [B*N]
{
    const int i = threadIdx.x;         // 0..191 == b*Nn+n
    if (i >= Bn * Nn) return;
    const float ymin = boxes[i * 4 + 0];
    const float xmin = boxes[i * 4 + 1];
    const float ymax = boxes[i * 4 + 2];
    const float xmax = boxes[i * 4 + 3];
    const float h  = ymax - ymin;
    const float w  = xmax - xmin;
    const float pw = h * 0.5f;            // SCALE = 0.5
    const float ph = 1.0f * pw;           // ASPECT = 1.0
    const float oy = ymin + h * 0.5f;
    const float ox = xmin + w * 0.5f;
    float yp = fmaxf(oy - ph * 0.5f, 0.0f);
    float xp = fmaxf(ox - pw * 0.5f, 0.0f);
    yp = (yp + ph > (float)Hh) ? ((float)Hh - ph) : yp;
    xp = (xp + pw > (float)Ww) ? ((float)Ww - pw) : xp;

    BoxP p;
    p.y0b = (int)yp;                      // tf.cast truncation (>=0)
    p.x0b = (int)xp;
    p.hI  = (int)ph;
    p.wI  = (int)pw;
    const float hf = (float)(p.hI > 1 ? p.hI : 1);
    const float wf = (float)(p.wI > 1 ? p.wI : 1);
    p.syscale = (float)Pp / hf;           // identical op order to reference
    p.winv    = (float)Pp / wf;
    p.valid   = (ph > 60.0f) ? 1 : 0;     // MIN_PH
    p.pad     = 0;
    bp[i] = p;
}

// ---- per-stage state (all statically named -> stays in registers) ----
struct Cov {                 // coverage of a 2-pixel pair
    int   off0, off1;        // patch byte offset of low-row 6-float group
    float wx0, wy0, wx1, wy1;
    int   c0, c1;            // covered flags
};
struct Pk {                  // one pixel's 4 patch loads (2 rows x 6 floats)
    f32x4u a0; f32x2u a1;    // row yl  : cols xl, xl+1
    f32x4u b0; f32x2u b1;    // row yl+1
};
struct St {                  // one iteration's in-flight data
    Pk p0, p1;
    f32x4u i0; f32x2u i1;    // image fallback (6 floats of the pair span)
};

__device__ __forceinline__ Cov pass1(const BoxP* __restrict__ bp,
                                     int y, int x0) {
    Cov c;
    c.off0 = 0; c.off1 = 0;
    c.wx0 = 0.f; c.wy0 = 0.f; c.wx1 = 0.f; c.wy1 = 0.f;
    c.c0 = 0; c.c1 = 0;
    #pragma unroll
    for (int n = Nn - 1; n >= 0; --n) {   // descending: first hit == last writer
        // y is block-uniform -> pure SALU rejection with uniform branch
        const int y0b = bp[n].y0b;
        const int hI  = bp[n].hI;
        const int dy  = y - y0b;
        if (!(bp[n].valid && dy >= 0 && dy < hI)) continue;

        const int   x0b     = bp[n].x0b;
        const int   wI      = bp[n].wI;
        const float syscale = bp[n].syscale;
        const float winv    = bp[n].winv;

        float sy = ((float)dy + 0.5f) * syscale - 0.5f;
        sy = fminf(fmaxf(sy, 0.0f), (float)(Pp - 1));
        int yl = (int)sy;                     // == floor (sy >= 0)
        yl = (yl > Pp - 2) ? (Pp - 2) : yl;   // yh = yl+1 always; wy==1 -> row 511
        const float wyv = sy - (float)yl;
        const int rl = yl * (Pp * 3 * 4);     // 6144 B per patch row

        {   // pixel 0 of the pair
            const int dx = x0 - x0b;
            float sx = ((float)dx + 0.5f) * winv - 0.5f;
            sx = fminf(fmaxf(sx, 0.0f), (float)(Pp - 1));
            int xl = (int)sx;
            xl = (xl > Pp - 2) ? (Pp - 2) : xl;
            const float wxv = sx - (float)xl;
            if ((dx >= 0) & (dx < wI) & (c.c0 == 0)) {
                c.c0 = 1; c.off0 = rl + xl * 12; c.wx0 = wxv; c.wy0 = wyv;
            }
        }
        {   // pixel 1
            const int dx = x0 + 1 - x0b;
            float sx = ((float)dx + 0.5f) * winv - 0.5f;
            sx = fminf(fmaxf(sx, 0.0f), (float)(Pp - 1));
            int xl = (int)sx;
            xl = (xl > Pp - 2) ? (Pp - 2) : xl;
            const float wxv = sx - (float)xl;
            if ((dx >= 0) & (dx < wI) & (c.c1 == 0)) {
                c.c1 = 1; c.off1 = rl + xl * 12; c.wx1 = wxv; c.wy1 = wyv;
            }
        }
    }
    return c;
}

__device__ __forceinline__ St issue(const Cov& c,
                                    const char* __restrict__ pbytes,
                                    const float* __restrict__ images,
                                    size_t fbase) {
    St s;
    s.i0 = (f32x4u){0.f, 0.f, 0.f, 0.f};
    s.i1 = (f32x2u){0.f, 0.f};
    // image fallback (predicated per-lane; nt keeps L2 for the patch)
    if (!(c.c0 & c.c1)) {
        s.i0 = __builtin_nontemporal_load((const f32x4u*)(images + fbase));
        s.i1 = __builtin_nontemporal_load((const f32x2u*)(images + fbase + 4));
    }
    s.p0.a0 = (f32x4u){0.f,0.f,0.f,0.f}; s.p0.a1 = (f32x2u){0.f,0.f};
    s.p0.b0 = s.p0.a0; s.p0.b1 = s.p0.a1;
    s.p1 = s.p0;
    if (__any(c.c0 | c.c1)) {            // wave-uniform skip when no coverage
        // uncovered lanes read patch[0..24) harmlessly (off==0)
        s.p0.a0 = *(const f32x4u*)(pbytes + c.off0);
        s.p0.a1 = *(const f32x2u*)(pbytes + c.off0 + 16);
        s.p0.b0 = *(const f32x4u*)(pbytes + c.off0 + 6144);
        s.p0.b1 = *(const f32x2u*)(pbytes + c.off0 + 6160);
        s.p1.a0 = *(const f32x4u*)(pbytes + c.off1);
        s.p1.a1 = *(const f32x2u*)(pbytes + c.off1 + 16);
        s.p1.b0 = *(const f32x4u*)(pbytes + c.off1 + 6144);
        s.p1.b1 = *(const f32x2u*)(pbytes + c.off1 + 6160);
    }
    return s;
}

__device__ __forceinline__ void bilin(const Pk& p, float wyv, float wxv,
                                      float* __restrict__ r3) {
    const float omy = 1.0f - wyv, omx = 1.0f - wxv;
    const float A[6] = {p.a0.x, p.a0.y, p.a0.z, p.a0.w, p.a1.x, p.a1.y};
    const float B[6] = {p.b0.x, p.b0.y, p.b0.z, p.b0.w, p.b1.x, p.b1.y};
    #pragma unroll
    for (int cc = 0; cc < 3; ++cc) {
        // same op order as reference: rows over y, then x
        r3[cc] = (A[cc]     * omy + B[cc]     * wyv) * omx
               + (A[3 + cc] * omy + B[3 + cc] * wyv) * wxv;
    }
}

__device__ __forceinline__ void consume_store(const Cov& c, const St& s,
                                              float* __restrict__ out,
                                              size_t fbase) {
    float r[6];
    if (c.c0) {
        bilin(s.p0, c.wy0, c.wx0, &r[0]);
    } else {
        r[0] = s.i0.x; r[1] = s.i0.y; r[2] = s.i0.z;
    }
    if (c.c1) {
        bilin(s.p1, c.wy1, c.wx1, &r[3]);
    } else {
        r[3] = s.i0.w; r[4] = s.i1.x; r[5] = s.i1.y;
    }
    // normal (allocating) stores: L2 merges 24B-stride lanes into full lines
    f32x4u v0; v0.x = r[0]; v0.y = r[1]; v0.z = r[2]; v0.w = r[3];
    f32x2u v1; v1.x = r[4]; v1.y = r[5];
    *(f32x4u*)(out + fbase)     = v0;
    *(f32x2u*)(out + fbase + 4) = v1;
}

__global__ __launch_bounds__(256, 4) void patch_attack_kernel(
    const float* __restrict__ images,  // [B,H,W,3]
    const BoxP* __restrict__ bparams,  // [B*N] from setup kernel
    const float* __restrict__ patch,   // [P,P,3]
    float* __restrict__ out)           // [B,H,W,3]
{
    const int tid = threadIdx.x;
    const int blk = blockIdx.x;                        // 4096 blocks
    // block = 4 consecutive rows of one image; iter i handles row y0+i.
    const int b  = __builtin_amdgcn_readfirstlane(blk >> 7);        // 128 blk/img
    const int y0 = __builtin_amdgcn_readfirstlane((blk & 127) << 2);
    const int x0 = tid << 1;                           // pixel x of the pair

    const BoxP* __restrict__ bp = bparams + b * Nn;
    const char* __restrict__ pbytes = (const char*)patch;

    // float offset of this thread's pair in row y0+i:  base + i*1536
    const size_t base = (size_t)b * (Hh * Ww * 3) + (size_t)y0 * (Ww * 3)
                      + (size_t)tid * 6;

    // ---- fully-unrolled 4-iteration, 2-deep software pipeline ----
    Cov c0 = pass1(bp, y0 + 0, x0);
    St  s0 = issue(c0, pbytes, images, base);

    Cov c1 = pass1(bp, y0 + 1, x0);
    St  s1 = issue(c1, pbytes, images, base + 1536);

    consume_store(c0, s0, out, base);

    Cov c2 = pass1(bp, y0 + 2, x0);
    St  s2 = issue(c2, pbytes, images, base + 3072);

    consume_store(c1, s1, out, base + 1536);

    Cov c3 = pass1(bp, y0 + 3, x0);
    St  s3 = issue(c3, pbytes, images, base + 4608);

    consume_store(c2, s2, out, base + 3072);
    consume_store(c3, s3, out, base + 4608);
}

extern "C" void kernel_launch(void* const* d_in, const int* in_sizes, int n_in,
                              void* d_out, int out_size, void* d_ws, size_t ws_size,
                              hipStream_t stream) {
    const float* images = (const float*)d_in[0];
    const float* boxes  = (const float*)d_in[1];
    const float* patch  = (const float*)d_in[2];
    float* out = (float*)d_out;
    BoxP* bp = (BoxP*)d_ws;            // 32*6*32 B = 6 KB of workspace

    box_setup_kernel<<<1, 192, 0, stream>>>(boxes, bp);

    // 32 images x 128 row-quads = 4096 blocks; 256 threads x 4 iters x 2 px
    patch_attack_kernel<<<4096, 256, 0, stream>>>(images, bp, patch, out);
}

// Round 7
// 194.858 us; speedup vs baseline: 1.6918x; 1.6918x over previous
//
#include <hip/hip_runtime.h>

// PatchAttacker: B=32 images 512x512x3, N=6 boxes, patch 512x512x3.
// Final pixel = bilinear(patch) of the LAST valid covering patch box, else image.
// v7: max-TLP, plain-memory, sync-free.
//   Post-mortem of v1-v6: time pinned at 62-65us across 5 structures; v6's ILP
//   pipeline spilled to scratch (VGPR 32, WRITE 525MB) and regressed. v1
//   (plain allocating loads/stores, most waves) remains the fastest dispatch
//   and highest BW. So: v5's proven SALU pass-1 (setup-kernel box params,
//   wave-uniform rejection) + v1's memory philosophy (NO nt hints, no LDS, no
//   barrier) + 2 px/thread (4.2M threads, VGPR ~40, 8 waves/SIMD, waves retire
//   independently). All FP formulas bit-identical to v5 (absmax 0.0).

#define Bn 32
#define Nn 6
#define Hh 512
#define Ww 512
#define Pp 512

typedef float f32x4u __attribute__((ext_vector_type(4), aligned(4)));
typedef float f32x2u __attribute__((ext_vector_type(2), aligned(4)));

struct BoxP {
    int   y0b, x0b, hI, wI;
    float syscale, winv;
    int   valid, pad;
};

__global__ __launch_bounds__(192) void box_setup_kernel(
    const float* __restrict__ boxes,   // [B,N,4]
    BoxP* __restrict__ bp)             // [B*N]
{
    const int i = threadIdx.x;         // 0..191 == b*Nn+n
    if (i >= Bn * Nn) return;
    const float ymin = boxes[i * 4 + 0];
    const float xmin = boxes[i * 4 + 1];
    const float ymax = boxes[i * 4 + 2];
    const float xmax = boxes[i * 4 + 3];
    const float h  = ymax - ymin;
    const float w  = xmax - xmin;
    const float pw = h * 0.5f;            // SCALE = 0.5
    const float ph = 1.0f * pw;           // ASPECT = 1.0
    const float oy = ymin + h * 0.5f;
    const float ox = xmin + w * 0.5f;
    float yp = fmaxf(oy - ph * 0.5f, 0.0f);
    float xp = fmaxf(ox - pw * 0.5f, 0.0f);
    yp = (yp + ph > (float)Hh) ? ((float)Hh - ph) : yp;
    xp = (xp + pw > (float)Ww) ? ((float)Ww - pw) : xp;

    BoxP p;
    p.y0b = (int)yp;                      // tf.cast truncation (>=0)
    p.x0b = (int)xp;
    p.hI  = (int)ph;
    p.wI  = (int)pw;
    const float hf = (float)(p.hI > 1 ? p.hI : 1);
    const float wf = (float)(p.wI > 1 ? p.wI : 1);
    p.syscale = (float)Pp / hf;           // identical op order to reference
    p.winv    = (float)Pp / wf;
    p.valid   = (ph > 60.0f) ? 1 : 0;     // MIN_PH
    p.pad     = 0;
    bp[i] = p;
}

__global__ __launch_bounds__(256) void patch_attack_kernel(
    const float* __restrict__ images,  // [B,H,W,3]
    const BoxP* __restrict__ bparams,  // [B*N] from setup kernel
    const float* __restrict__ patch,   // [P,P,3]
    float* __restrict__ out)           // [B,H,W,3]
{
    const int tid = threadIdx.x;
    const int gid = blockIdx.x * 256 + tid;           // pixel-pair id (4,194,304)
    // 131072 pairs/image (block never spans images); 256 pairs/row
    // (wave = 64 pairs = 128 contiguous px, never spans rows) -> b,y uniform.
    const int b   = __builtin_amdgcn_readfirstlane(gid >> 17);
    const int rem = gid & 131071;
    const int y   = __builtin_amdgcn_readfirstlane(rem >> 8);
    const int x0  = (rem & 255) << 1;                 // pixel x of the pair

    const BoxP* __restrict__ bp = bparams + b * Nn;

    // ---------------- pass 1: coverage resolution (SALU rejection) ----------
    int   bid0 = -1, bid1 = -1;
    int   off0 = 0,  off1 = 0;         // patch byte offset of low-row group
    float wx0 = 0.f, wy0 = 0.f, wx1 = 0.f, wy1 = 0.f;

    #pragma unroll
    for (int n = Nn - 1; n >= 0; --n) {   // descending: first hit == last writer
        const int y0b = bp[n].y0b;        // wave-uniform -> s_load + SALU test
        const int hI  = bp[n].hI;
        const int dy  = y - y0b;
        if (!(bp[n].valid && dy >= 0 && dy < hI)) continue;

        const int   x0b     = bp[n].x0b;
        const int   wI      = bp[n].wI;
        const float syscale = bp[n].syscale;
        const float winv    = bp[n].winv;

        float sy = ((float)dy + 0.5f) * syscale - 0.5f;
        sy = fminf(fmaxf(sy, 0.0f), (float)(Pp - 1));
        int yl = (int)sy;                     // == floor (sy >= 0)
        yl = (yl > Pp - 2) ? (Pp - 2) : yl;   // yh = yl+1 always; wy==1 -> row 511
        const float wyv = sy - (float)yl;
        const int rl = yl * (Pp * 3 * 4);     // 6144 B per patch row

        {   // pixel 0
            const int dx = x0 - x0b;
            float sx = ((float)dx + 0.5f) * winv - 0.5f;
            sx = fminf(fmaxf(sx, 0.0f), (float)(Pp - 1));
            int xl = (int)sx;
            xl = (xl > Pp - 2) ? (Pp - 2) : xl;
            const float wxv = sx - (float)xl;
            if ((dx >= 0) & (dx < wI) & (bid0 < 0)) {
                bid0 = n; off0 = rl + xl * 12; wx0 = wxv; wy0 = wyv;
            }
        }
        {   // pixel 1
            const int dx = x0 + 1 - x0b;
            float sx = ((float)dx + 0.5f) * winv - 0.5f;
            sx = fminf(fmaxf(sx, 0.0f), (float)(Pp - 1));
            int xl = (int)sx;
            xl = (xl > Pp - 2) ? (Pp - 2) : xl;
            const float wxv = sx - (float)xl;
            if ((dx >= 0) & (dx < wI) & (bid1 < 0)) {
                bid1 = n; off1 = rl + xl * 12; wx1 = wxv; wy1 = wyv;
            }
        }
    }

    // -------- image fallback: plain (allocating) loads, issued early --------
    const bool c0 = bid0 >= 0, c1 = bid1 >= 0;
    f32x4u i0 = {0.f, 0.f, 0.f, 0.f};
    f32x2u i1 = {0.f, 0.f};
    const size_t fbase = (size_t)gid * 6;             // float offset of the pair
    if (!(c0 & c1)) {
        i0 = *(const f32x4u*)(images + fbase);
        i1 = *(const f32x2u*)(images + fbase + 4);
    }

    // ---------------- patch gathers (plain) + bilinear ----------------------
    float pr[6] = {0.f, 0.f, 0.f, 0.f, 0.f, 0.f};
    const char* __restrict__ pb = (const char*)patch;
    if (__any(c0 | c1)) {
        // uncovered lanes read patch[0..24) harmlessly (off==0); offsets are
        // multiples of 4 -> 4B-aligned vector loads (proven in v4b/v5).
        const f32x4u a00 = *(const f32x4u*)(pb + off0);          // px0 row yl
        const f32x2u a01 = *(const f32x2u*)(pb + off0 + 16);
        const f32x4u b00 = *(const f32x4u*)(pb + off0 + 6144);   // px0 row yl+1
        const f32x2u b01 = *(const f32x2u*)(pb + off0 + 6160);
        const f32x4u a10 = *(const f32x4u*)(pb + off1);          // px1 row yl
        const f32x2u a11 = *(const f32x2u*)(pb + off1 + 16);
        const f32x4u b10 = *(const f32x4u*)(pb + off1 + 6144);   // px1 row yl+1
        const f32x2u b11 = *(const f32x2u*)(pb + off1 + 6160);
        {
            const float omy = 1.0f - wy0, omx = 1.0f - wx0;
            const float A[6]  = {a00.x, a00.y, a00.z, a00.w, a01.x, a01.y};
            const float Bv[6] = {b00.x, b00.y, b00.z, b00.w, b01.x, b01.y};
            #pragma unroll
            for (int c = 0; c < 3; ++c)   // same op order as reference
                pr[c] = (A[c]     * omy + Bv[c]     * wy0) * omx
                      + (A[3 + c] * omy + Bv[3 + c] * wy0) * wx0;
        }
        {
            const float omy = 1.0f - wy1, omx = 1.0f - wx1;
            const float A[6]  = {a10.x, a10.y, a10.z, a10.w, a11.x, a11.y};
            const float Bv[6] = {b10.x, b10.y, b10.z, b10.w, b11.x, b11.y};
            #pragma unroll
            for (int c = 0; c < 3; ++c)
                pr[3 + c] = (A[c]     * omy + Bv[c]     * wy1) * omx
                          + (A[3 + c] * omy + Bv[3 + c] * wy1) * wx1;
        }
    }

    // ---------------- select + plain direct stores (no LDS, no barrier) -----
    float r[6];
    r[0] = c0 ? pr[0] : i0.x;
    r[1] = c0 ? pr[1] : i0.y;
    r[2] = c0 ? pr[2] : i0.z;
    r[3] = c1 ? pr[3] : i0.w;
    r[4] = c1 ? pr[4] : i1.x;
    r[5] = c1 ? pr[5] : i1.y;

    f32x4u v0; v0.x = r[0]; v0.y = r[1]; v0.z = r[2]; v0.w = r[3];
    f32x2u v1; v1.x = r[4]; v1.y = r[5];
    *(f32x4u*)(out + fbase)     = v0;    // plain allocating stores: L2 merges
    *(f32x2u*)(out + fbase + 4) = v1;    // 24B-stride lanes (v1 counter proof)
}

extern "C" void kernel_launch(void* const* d_in, const int* in_sizes, int n_in,
                              void* d_out, int out_size, void* d_ws, size_t ws_size,
                              hipStream_t stream) {
    const float* images = (const float*)d_in[0];
    const float* boxes  = (const float*)d_in[1];
    const float* patch  = (const float*)d_in[2];
    float* out = (float*)d_out;
    BoxP* bp = (BoxP*)d_ws;            // 32*6*32 B = 6 KB of workspace

    box_setup_kernel<<<1, 192, 0, stream>>>(boxes, bp);

    // 4,194,304 pixel pairs / 256 threads = 16384 blocks
    patch_attack_kernel<<<16384, 256, 0, stream>>>(images, bp, patch, out);
}

// Round 8
// 188.391 us; speedup vs baseline: 1.7498x; 1.0343x over previous
//
#include <hip/hip_runtime.h>

// PatchAttacker: B=32 images 512x512x3, N=6 boxes, patch 512x512x3.
// Final pixel = bilinear(patch) of the LAST valid covering patch box, else image.
// v8: LDS row-staging to kill scattered L1 gathers.
//   Diagnosis across v1-v7: dur pinned at 62-65us while bytes (151-183MB), BW
//   (1.9-2.9 TB/s), VALU (15-56%) all varied -> the invariant bottleneck is the
//   per-lane scattered patch gathers (each wave-instr touches ~64 cache lines;
//   ~500 L1 line-requests per covered wave ~= the entire kernel duration at
//   ~1 line/cy/CU). Fix: block = one image row -> y block-uniform -> per box
//   all pixels need the SAME two patch rows = 12,288 CONTIGUOUS bytes
//   (yh=yl+1 by clamp). Stage them into LDS with 3 dense dwordx4/thread
//   (minimum possible line count), bilinear-gather from LDS instead of L1.
//   Box staging loop gated by __syncthreads_or. Pass-1 (registers-only
//   coverage, identical math), predicated nt image loads, plain stores all
//   unchanged from v7/v5.

#define Bn 32
#define Nn 6
#define Hh 512
#define Ww 512
#define Pp 512

typedef float f32x4 __attribute__((ext_vector_type(4)));
typedef float f32x4u __attribute__((ext_vector_type(4), aligned(4)));
typedef float f32x2u __attribute__((ext_vector_type(2), aligned(4)));

struct BoxP {
    int   y0b, x0b, hI, wI;
    float syscale, winv;
    int   valid, pad;
};

__global__ __launch_bounds__(192) void box_setup_kernel(
    const float* __restrict__ boxes,   // [B,N,4]
    BoxP* __restrict__ bp)             // [B*N]
{
    const int i = threadIdx.x;         // 0..191 == b*Nn+n
    if (i >= Bn * Nn) return;
    const float ymin = boxes[i * 4 + 0];
    const float xmin = boxes[i * 4 + 1];
    const float ymax = boxes[i * 4 + 2];
    const float xmax = boxes[i * 4 + 3];
    const float h  = ymax - ymin;
    const float w  = xmax - xmin;
    const float pw = h * 0.5f;            // SCALE = 0.5
    const float ph = 1.0f * pw;           // ASPECT = 1.0
    const float oy = ymin + h * 0.5f;
    const float ox = xmin + w * 0.5f;
    float yp = fmaxf(oy - ph * 0.5f, 0.0f);
    float xp = fmaxf(ox - pw * 0.5f, 0.0f);
    yp = (yp + ph > (float)Hh) ? ((float)Hh - ph) : yp;
    xp = (xp + pw > (float)Ww) ? ((float)Ww - pw) : xp;

    BoxP p;
    p.y0b = (int)yp;                      // tf.cast truncation (>=0)
    p.x0b = (int)xp;
    p.hI  = (int)ph;
    p.wI  = (int)pw;
    const float hf = (float)(p.hI > 1 ? p.hI : 1);
    const float wf = (float)(p.wI > 1 ? p.wI : 1);
    p.syscale = (float)Pp / hf;           // identical op order to reference
    p.winv    = (float)Pp / wf;
    p.valid   = (ph > 60.0f) ? 1 : 0;     // MIN_PH
    p.pad     = 0;
    bp[i] = p;
}

__global__ __launch_bounds__(256) void patch_attack_kernel(
    const float* __restrict__ images,  // [B,H,W,3]
    const BoxP* __restrict__ bparams,  // [B*N] from setup kernel
    const float* __restrict__ patch,   // [P,P,3]
    float* __restrict__ out)           // [B,H,W,3]
{
    __shared__ f32x4 lds4[768];        // 12,288 B = patch rows yl, yl+1
    float* __restrict__ ldsf = (float*)lds4;

    const int tid = threadIdx.x;
    // block = one image row: b and y are true scalars (from blockIdx)
    const int b   = blockIdx.x >> 9;
    const int y   = blockIdx.x & 511;
    const int x0  = tid << 1;          // this thread's pixel pair: x0, x0+1

    const BoxP* __restrict__ bp = bparams + b * Nn;

    // ------------- pass 1: registers-only coverage (math == v7) -------------
    int   bid0 = -1, bid1 = -1;
    int   xls0 = 0,  xls1 = 0;         // xl index (0..510)
    float wx0 = 0.f, wy0 = 0.f, wx1 = 0.f, wy1 = 0.f;

    #pragma unroll
    for (int n = Nn - 1; n >= 0; --n) {   // descending: first hit == last writer
        const int y0b = bp[n].y0b;        // scalar -> SALU row rejection
        const int hI  = bp[n].hI;
        const int dy  = y - y0b;
        if (!(bp[n].valid && dy >= 0 && dy < hI)) continue;

        const int   x0b     = bp[n].x0b;
        const int   wI      = bp[n].wI;
        const float syscale = bp[n].syscale;
        const float winv    = bp[n].winv;

        float sy = ((float)dy + 0.5f) * syscale - 0.5f;
        sy = fminf(fmaxf(sy, 0.0f), (float)(Pp - 1));
        int yl = (int)sy;                     // == floor (sy >= 0)
        yl = (yl > Pp - 2) ? (Pp - 2) : yl;   // yh = yl+1 always; wy==1 -> row 511
        const float wyv = sy - (float)yl;

        {   // pixel 0
            const int dx = x0 - x0b;
            float sx = ((float)dx + 0.5f) * winv - 0.5f;
            sx = fminf(fmaxf(sx, 0.0f), (float)(Pp - 1));
            int xl = (int)sx;
            xl = (xl > Pp - 2) ? (Pp - 2) : xl;
            const float wxv = sx - (float)xl;
            if ((dx >= 0) & (dx < wI) & (bid0 < 0)) {
                bid0 = n; xls0 = xl; wx0 = wxv; wy0 = wyv;
            }
        }
        {   // pixel 1
            const int dx = x0 + 1 - x0b;
            float sx = ((float)dx + 0.5f) * winv - 0.5f;
            sx = fminf(fmaxf(sx, 0.0f), (float)(Pp - 1));
            int xl = (int)sx;
            xl = (xl > Pp - 2) ? (Pp - 2) : xl;
            const float wxv = sx - (float)xl;
            if ((dx >= 0) & (dx < wI) & (bid1 < 0)) {
                bid1 = n; xls1 = xl; wx1 = wxv; wy1 = wyv;
            }
        }
    }

    // ------- image fallback: predicated nt loads, issued early (v5) -------
    const bool c0 = bid0 >= 0, c1 = bid1 >= 0;
    f32x4u i0 = {0.f, 0.f, 0.f, 0.f};
    f32x2u i1 = {0.f, 0.f};
    const size_t fbase = ((size_t)blockIdx.x * 512 + (size_t)x0) * 3;
    if (!(c0 & c1)) {
        i0 = __builtin_nontemporal_load((const f32x4u*)(images + fbase));
        i1 = __builtin_nontemporal_load((const f32x2u*)(images + fbase + 4));
    }

    // ------------- staging loop: dense row copy -> LDS bilinear -------------
    float pr[6] = {0.f, 0.f, 0.f, 0.f, 0.f, 0.f};
    #pragma unroll
    for (int n = Nn - 1; n >= 0; --n) {
        // block-uniform row test (same predicate as pass 1)
        const int y0b = bp[n].y0b;
        const int hI  = bp[n].hI;
        const int dy  = y - y0b;
        if (!(bp[n].valid && dy >= 0 && dy < hI)) continue;

        const int hit0 = (bid0 == n), hit1 = (bid1 == n);
        // block-wide need test; also orders prior consume vs. this staging
        if (!__syncthreads_or(hit0 | hit1)) continue;

        // recompute yl (block-uniform, same formula as pass 1)
        float sy = ((float)dy + 0.5f) * bp[n].syscale - 0.5f;
        sy = fminf(fmaxf(sy, 0.0f), (float)(Pp - 1));
        int yl = (int)sy;
        yl = (yl > Pp - 2) ? (Pp - 2) : yl;

        // rows yl and yl+1 are 12,288 CONTIGUOUS bytes; 16B-aligned
        const char* __restrict__ src = (const char*)patch + (size_t)yl * 6144;
        const f32x4 t0 = *(const f32x4*)(src + (size_t)tid * 16);
        const f32x4 t1 = *(const f32x4*)(src + 4096 + (size_t)tid * 16);
        const f32x4 t2 = *(const f32x4*)(src + 8192 + (size_t)tid * 16);
        lds4[tid]       = t0;          // dense ds_write_b128, conflict-free
        lds4[tid + 256] = t1;
        lds4[tid + 512] = t2;
        __syncthreads();

        if (hit0) {                    // 12 LDS floats, bilinear (ref op order)
            const int o = xls0 * 3;
            const float omy = 1.0f - wy0, omx = 1.0f - wx0;
            #pragma unroll
            for (int c = 0; c < 3; ++c)
                pr[c] = (ldsf[o + c]     * omy + ldsf[1536 + o + c]     * wy0) * omx
                      + (ldsf[o + 3 + c] * omy + ldsf[1536 + o + 3 + c] * wy0) * wx0;
        }
        if (hit1) {
            const int o = xls1 * 3;
            const float omy = 1.0f - wy1, omx = 1.0f - wx1;
            #pragma unroll
            for (int c = 0; c < 3; ++c)
                pr[3 + c] = (ldsf[o + c]     * omy + ldsf[1536 + o + c]     * wy1) * omx
                          + (ldsf[o + 3 + c] * omy + ldsf[1536 + o + 3 + c] * wy1) * wx1;
        }
        // next iteration's __syncthreads_or orders consume before re-staging
    }

    // ---------------- select + plain direct stores (v7, proven) -------------
    float r[6];
    r[0] = c0 ? pr[0] : i0.x;
    r[1] = c0 ? pr[1] : i0.y;
    r[2] = c0 ? pr[2] : i0.z;
    r[3] = c1 ? pr[3] : i0.w;
    r[4] = c1 ? pr[4] : i1.x;
    r[5] = c1 ? pr[5] : i1.y;

    f32x4u v0; v0.x = r[0]; v0.y = r[1]; v0.z = r[2]; v0.w = r[3];
    f32x2u v1; v1.x = r[4]; v1.y = r[5];
    *(f32x4u*)(out + fbase)     = v0;  // plain allocating stores: L2 merges
    *(f32x2u*)(out + fbase + 4) = v1;  // (WRITE_SIZE == exact, v1/v7 proof)
}

extern "C" void kernel_launch(void* const* d_in, const int* in_sizes, int n_in,
                              void* d_out, int out_size, void* d_ws, size_t ws_size,
                              hipStream_t stream) {
    const float* images = (const float*)d_in[0];
    const float* boxes  = (const float*)d_in[1];
    const float* patch  = (const float*)d_in[2];
    float* out = (float*)d_out;
    BoxP* bp = (BoxP*)d_ws;            // 32*6*32 B = 6 KB of workspace

    box_setup_kernel<<<1, 192, 0, stream>>>(boxes, bp);

    // block = one image row: 32 images x 512 rows = 16384 blocks
    patch_attack_kernel<<<16384, 256, 0, stream>>>(images, bp, patch, out);
}